// Round 12
// baseline (93.947 us; speedup 1.0000x reference)
//
#include <hip/hip_runtime.h>

#define NBATCH 4096
#define SEQ 512
#define HID 5
#define NEMB 64

__device__ __forceinline__ float frcp(float x){ return __builtin_amdgcn_rcpf(x); }

// Pade [5/4] tanh (continued-fraction truncation), input clamped to +-3.5.
// max err ~1.5e-3 vs tanh; one rcp, no exp2.
__device__ __forceinline__ float pade_tanh(float y) {
    y = fminf(fmaxf(y, -3.5f), 3.5f);
    float z = y * y;
    float n = y * fmaf(z, z + 105.0f, 945.0f);          // y*(z^2+105z+945)
    float d = fmaf(z, fmaf(z, 15.0f, 420.0f), 945.0f);  // 15z^2+420z+945
    return n * frcp(d);
}

// ds_swizzle BitMode: all lanes of each 32-half read lane 4k
#define SWZ(v, k) __int_as_float(__builtin_amdgcn_ds_swizzle(__float_as_int(v), ((4*(k)) << 5)))
// quad_perm broadcast of quad-lane j to the whole quad
#define DPPQ(v, j) __int_as_float(__builtin_amdgcn_update_dpp(0, __float_as_int(v), ((j) * 0x55), 0xF, 0xF, true))

__global__ __launch_bounds__(64) void lstm_enc_kernel(
    const float* __restrict__ x_num, const int* __restrict__ x_cat,
    const float* __restrict__ embed, const float* __restrict__ W_ih,
    const float* __restrict__ W_hh, const float* __restrict__ b_ih,
    const float* __restrict__ b_hh, float* __restrict__ out)
{
    __shared__ float4 s_emb[NEMB];
    int tid = threadIdx.x;
    s_emb[tid] = ((const float4*)embed)[tid];
    __syncthreads();

    // 2 batch elements per wave, one per 32-lane half (r6/r11 layout).
    // lane l in half: quad q=l>>2 owns unit k=min(q,4); g=l&3 is the gate.
    int halfi = tid >> 5;
    int l     = tid & 31;
    int b     = blockIdx.x * 2 + halfi;
    int k     = ((l >> 2) < HID) ? (l >> 2) : (HID - 1);
    int g     = l & 3;                      // 0:i 1:f 2:g 3:o
    bool st   = (l < 20) && (g == 0);       // h_k holder lanes: 0,4,8,12,16

    // sigmoid gates: sigma(x) = 0.5 + 0.5*tanh(x/2) -> prescale weights by 0.5
    // tanh gate (g==2): tanh(x) direct -> prescale 1.0
    float s_  = (g == 2) ? 1.0f : 0.5f;
    float fm  = (g == 2) ? 1.0f : 0.5f;     // v = t*fm + fb
    float fb  = (g == 2) ? 0.0f : 0.5f;

    int row = g * HID + k;
    float wi_[5], whz[5];
#pragma unroll
    for (int d = 0; d < 5; ++d) {
        wi_[d] = W_ih[row * 5 + d] * s_;
        whz[d] = W_hh[row * 5 + d] * s_;
    }
    float wh_own = whz[k];                  // own-unit h weight (h local post-DPPQ)
    whz[k] = 0.0f;                          // zero own index in broadcast weights

    const float4* xp = (const float4*)(x_num + (size_t)b * SEQ);
    const int4*   cp = (const int4*)(x_cat + (size_t)b * SEQ);
    float* outp = out + (size_t)b * SEQ * HID + k;
    float bias = (b_ih[row] + b_hh[row]) * s_;

    float h = 0.f, c = 0.f;
    float hb0 = 0.f, hb1 = 0.f, hb2 = 0.f, hb3 = 0.f, hb4 = 0.f;

    // depth-2 prefetch of x/cat; emb staged one block ahead
    float4 xf_c = xp[0];  int4 cf_c = cp[0];
    float4 xf_1 = xp[1];  int4 cf_1 = cp[1];
    float4 ec_c[4];
    ec_c[0] = s_emb[cf_c.x]; ec_c[1] = s_emb[cf_c.y];
    ec_c[2] = s_emb[cf_c.z]; ec_c[3] = s_emb[cf_c.w];

    // prologue: xa for t=0
    float xa_cur;
    {
        float4 e = ec_c[0];
        float a = fmaf(xf_c.x, wi_[0], bias);
        a = fmaf(e.x, wi_[1], a);
        a = fmaf(e.y, wi_[2], a);
        a = fmaf(e.z, wi_[3], a);
        a = fmaf(e.w, wi_[4], a);
        xa_cur = a;
    }

    for (int t0 = 0; t0 < SEQ; t0 += 4) {
        int n2 = (t0 >> 2) + 2;
        if (n2 > (SEQ / 4 - 1)) n2 = SEQ / 4 - 1;
        float4 xf_2 = xp[n2];
        int4   cf_2 = cp[n2];

        // next block's emb rows (cf_1 is a full block old -> long-landed)
        float4 ec_n0 = s_emb[cf_1.x];
        float4 ec_n1 = s_emb[cf_1.y];
        float4 ec_n2 = s_emb[cf_1.z];
        float4 ec_n3 = s_emb[cf_1.w];

        float xn_a[4] = {xf_c.x, xf_c.y, xf_c.z, xf_c.w};

#pragma unroll
        for (int u = 0; u < 4; ++u) {
            // ---- recurrent chain ----
            float a = fmaf(h, wh_own, xa_cur);
            a = fmaf(hb0, whz[0], a);
            a = fmaf(hb1, whz[1], a);
            a = fmaf(hb2, whz[2], a);
            a = fmaf(hb3, whz[3], a);
            a = fmaf(hb4, whz[4], a);

            // one Pade activation per lane; sigma-gates fix up 0.5+0.5t
            float t = pade_tanh(a);
            float v = fmaf(t, fm, fb);

            float ai = DPPQ(v, 0);
            float af = DPPQ(v, 1);
            float ag = DPPQ(v, 2);
            float ao = DPPQ(v, 3);

            c = fmaf(af, c, ai * ag);
            float tc = pade_tanh(c);
            float hn = ao * tc;

            // issue next-step broadcasts IMMEDIATELY
            hb0 = SWZ(hn, 0);
            hb1 = SWZ(hn, 1);
            hb2 = SWZ(hn, 2);
            hb3 = SWZ(hn, 3);
            hb4 = SWZ(hn, 4);

            // ---- fill window: xa for step t+1 + store (independent of swizzles) ----
            {
                float xn_nxt = (u < 3) ? xn_a[u + 1] : xf_1.x;
                float4 e     = (u < 3) ? ec_c[u + 1] : ec_n0;
                float an = fmaf(xn_nxt, wi_[0], bias);
                an = fmaf(e.x, wi_[1], an);
                an = fmaf(e.y, wi_[2], an);
                an = fmaf(e.z, wi_[3], an);
                an = fmaf(e.w, wi_[4], an);
                xa_cur = an;
            }
            if (st) outp[(t0 + u) * HID] = hn;

            h = hn;
        }

        ec_c[0] = ec_n0; ec_c[1] = ec_n1; ec_c[2] = ec_n2; ec_c[3] = ec_n3;
        xf_c = xf_1; xf_1 = xf_2;
        cf_c = cf_1; cf_1 = cf_2;
    }

    if (st) {
        size_t base = (size_t)NBATCH * SEQ * HID;
        out[base + (size_t)b * HID + k] = h;                          // hT
        out[base + (size_t)NBATCH * HID + (size_t)b * HID + k] = c;   // cT
    }
}

extern "C" void kernel_launch(void* const* d_in, const int* in_sizes, int n_in,
                              void* d_out, int out_size, void* d_ws, size_t ws_size,
                              hipStream_t stream) {
    const float* x_num = (const float*)d_in[0];
    const int*   x_cat = (const int*)d_in[1];
    const float* embed = (const float*)d_in[2];
    const float* W_ih  = (const float*)d_in[3];
    const float* W_hh  = (const float*)d_in[4];
    const float* b_ih  = (const float*)d_in[5];
    const float* b_hh  = (const float*)d_in[6];
    float* out = (float*)d_out;

    dim3 grid(NBATCH / 2);   // 2048 blocks, 1 wave each -> 2 waves/SIMD
    dim3 block(64);
    hipLaunchKernelGGL(lstm_enc_kernel, grid, block, 0, stream,
                       x_num, x_cat, embed, W_ih, W_hh, b_ih, b_hh, out);
}